// Round 2
// baseline (461.504 us; speedup 1.0000x reference)
//
#include <hip/hip_runtime.h>
#include <math.h>

#ifndef M_PI
#define M_PI 3.14159265358979323846
#endif

// Static problem config (mirrors reference)
#define SS   129                 // density cube side
#define LL   224                 // padded/rotation cube side = ceil(129*sqrt(3))
#define LL2  (LL*LL)
#define LL3  (LL*LL*LL)
#define SS2  (SS*SS)
#define SS3  (SS*SS*SS)
#define CABS 0.2f
#define PAD  48                  // LL/2 - SS/2 = 112 - 64

// Slab bounds in forward-rotated grid coords (q-space):
// density-touch region is (47,177); rotate-back fringe needs [46.26,177.74].
#define BLO 45.5f
#define BHI 178.5f

struct Mat3 { float m[9]; };

// linspace(-1, 1, 224)[i]
__device__ __forceinline__ float nrm(int i) {
    return fmaf((float)i, 2.0f / 223.0f, -1.0f);
}

// forward map p -> q (padded-grid coords of the rotated sample point).
// MUST be the single shared expression for K1 and K2 (bitwise consistency).
__device__ __forceinline__ void qmap(const Mat3& M, int x, int y, int z,
                                     float& qx, float& qy, float& qz) {
    float bx = nrm(x), by = nrm(y), bz = nrm(z);
    float sx = fmaf(M.m[0], bx, fmaf(M.m[1], by, M.m[2] * bz));
    float sy = fmaf(M.m[3], bx, fmaf(M.m[4], by, M.m[5] * bz));
    float sz = fmaf(M.m[6], bx, fmaf(M.m[7], by, M.m[8] * bz));
    qx = fmaf(sx, 111.5f, 111.5f);   // (s+1)*0.5*(LL-1)
    qy = fmaf(sy, 111.5f, 111.5f);
    qz = fmaf(sz, 111.5f, 111.5f);
}

__device__ __forceinline__ bool in_slab(float qx, float qy, float qz) {
    return !(qx < BLO || qx > BHI || qy < BLO || qy > BHI || qz < BLO || qz > BHI);
}

// padded-volume fetch: zero outside the centered SS^3 region
__device__ __forceinline__ float fetch_d(const float* __restrict__ d, int z, int y, int x) {
    unsigned zz = (unsigned)(z - PAD), yy = (unsigned)(y - PAD), xx = (unsigned)(x - PAD);
    return (zz < (unsigned)SS && yy < (unsigned)SS && xx < (unsigned)SS)
        ? d[((int)zz * SS + (int)yy) * SS + (int)xx] : 0.0f;
}

// transmittance-volume fetch: zero outside [0,LL)^3
__device__ __forceinline__ float fetch_T(const float* __restrict__ T, int z, int y, int x) {
    unsigned zz = (unsigned)z, yy = (unsigned)y, xx = (unsigned)x;
    return (zz < (unsigned)LL && yy < (unsigned)LL && xx < (unsigned)LL)
        ? T[((int)zz * LL + (int)yy) * LL + (int)xx] : 0.0f;
}

__device__ __forceinline__ float tri_d(const float* __restrict__ d, float qz, float qy, float qx) {
    int x0 = (int)floorf(qx), y0 = (int)floorf(qy), z0 = (int)floorf(qz);
    float wx = qx - (float)x0, wy = qy - (float)y0, wz = qz - (float)z0;
    float c000 = fetch_d(d, z0,     y0,     x0    );
    float c001 = fetch_d(d, z0,     y0,     x0 + 1);
    float c010 = fetch_d(d, z0,     y0 + 1, x0    );
    float c011 = fetch_d(d, z0,     y0 + 1, x0 + 1);
    float c100 = fetch_d(d, z0 + 1, y0,     x0    );
    float c101 = fetch_d(d, z0 + 1, y0,     x0 + 1);
    float c110 = fetch_d(d, z0 + 1, y0 + 1, x0    );
    float c111 = fetch_d(d, z0 + 1, y0 + 1, x0 + 1);
    float a00 = c000 + wx * (c001 - c000);
    float a01 = c010 + wx * (c011 - c010);
    float a10 = c100 + wx * (c101 - c100);
    float a11 = c110 + wx * (c111 - c110);
    float b0  = a00 + wy * (a01 - a00);
    float b1  = a10 + wy * (a11 - a10);
    return b0 + wz * (b1 - b0);
}

__device__ __forceinline__ float tri_T(const float* __restrict__ T, float qz, float qy, float qx) {
    int x0 = (int)floorf(qx), y0 = (int)floorf(qy), z0 = (int)floorf(qz);
    float wx = qx - (float)x0, wy = qy - (float)y0, wz = qz - (float)z0;
    float c000 = fetch_T(T, z0,     y0,     x0    );
    float c001 = fetch_T(T, z0,     y0,     x0 + 1);
    float c010 = fetch_T(T, z0,     y0 + 1, x0    );
    float c011 = fetch_T(T, z0,     y0 + 1, x0 + 1);
    float c100 = fetch_T(T, z0 + 1, y0,     x0    );
    float c101 = fetch_T(T, z0 + 1, y0,     x0 + 1);
    float c110 = fetch_T(T, z0 + 1, y0 + 1, x0    );
    float c111 = fetch_T(T, z0 + 1, y0 + 1, x0 + 1);
    float a00 = c000 + wx * (c001 - c000);
    float a01 = c010 + wx * (c011 - c010);
    float a10 = c100 + wx * (c101 - c100);
    float a11 = c110 + wx * (c111 - c110);
    float b0  = a00 + wy * (a01 - a00);
    float b1  = a10 + wy * (a11 - a10);
    return b0 + wz * (b1 - b0);
}

// K1: rotated density, restricted to the slab B (write nothing outside)
__global__ __launch_bounds__(256) void k_rot_density(const float* __restrict__ d,
                                                     float* __restrict__ T, Mat3 R) {
    int i = blockIdx.x * 256 + threadIdx.x;
    if (i >= LL3) return;
    int x = i % LL; int r = i / LL; int y = r % LL; int z = r / LL;
    float qx, qy, qz; qmap(R, x, y, z, qx, qy, qz);
    if (!in_slab(qx, qy, qz)) return;          // 81% of voxels: no gather, no write
    T[i] = tri_d(d, qz, qy, qx);
}

// K2: reverse cumulative sum + exp, restricted per column to the slab z-interval
__global__ __launch_bounds__(64) void k_scan_exp(float* __restrict__ T, Mat3 R) {
    int col = blockIdx.x * 64 + threadIdx.x;
    if (col >= LL2) return;
    int x = col % LL, y = col / LL;
    // linear model: q_k(z) = q_k(0) + z * R[k][2]   (grid step == 1 voxel exactly)
    float q0x, q0y, q0z; qmap(R, x, y, 0, q0x, q0y, q0z);
    float q0[3] = { q0x, q0y, q0z };
    float zlo = 0.0f, zhi = 223.0f;
    #pragma unroll
    for (int k = 0; k < 3; ++k) {
        float m = R.m[k * 3 + 2];
        if (fabsf(m) > 1e-6f) {
            float t0 = (BLO - q0[k]) / m, t1 = (BHI - q0[k]) / m;
            zlo = fmaxf(zlo, fminf(t0, t1));
            zhi = fminf(zhi, fmaxf(t0, t1));
        } else if (q0[k] < BLO || q0[k] > BHI) {
            return;                             // column misses the slab
        }
    }
    int z1 = min(223, (int)floorf(zhi) + 2);
    int z0 = max(0,   (int)ceilf(zlo)  - 2);
    if (z0 > z1) return;
    // skip down to first in-slab z (exact same test as K1 -> never reads poison)
    int z = z1;
    for (; z >= z0; --z) {
        float qx, qy, qz; qmap(R, x, y, z, qx, qy, qz);
        if (in_slab(qx, qy, qz)) break;
    }
    float run = 0.0f;
    for (; z >= z0; --z) {
        float qx, qy, qz; qmap(R, x, y, z, qx, qy, qz);
        if (!in_slab(qx, qy, qz)) break;        // slab interval is contiguous
        int idx = z * LL2 + col;
        run += T[idx];
        T[idx] = __expf(-CABS * run);
    }
}

// K3: rotate transmittance back (RT = R^T), cropped to the SS^3 center
__global__ __launch_bounds__(256) void k_rot_back(const float* __restrict__ T,
                                                  float* __restrict__ U, Mat3 RT) {
    int i = blockIdx.x * 256 + threadIdx.x;
    if (i >= SS3) return;
    int x = i % SS; int r = i / SS; int y = r % SS; int z = r / SS;
    float qx, qy, qz; qmap(RT, x + PAD, y + PAD, z + PAD, qx, qy, qz);
    U[i] = tri_T(T, qz, qy, qx);
}

// K4: composite along view ray
__global__ __launch_bounds__(64) void k_finalize(const float* __restrict__ d,
                                                 const float* __restrict__ U0,
                                                 const float* __restrict__ U1,
                                                 float* __restrict__ out,
                                                 float r0r, float r0g, float r0b,
                                                 float r1r, float r1g, float r1b) {
    int col = blockIdx.x * 64 + threadIdx.x;
    if (col >= SS2) return;
    float run = 0.0f, a0 = 0.0f, a1 = 0.0f;
    #pragma unroll 4
    for (int z = SS - 1; z >= 0; --z) {
        int idx = z * SS2 + col;
        float dv = d[idx];
        run += dv;
        float w = dv * __expf(-CABS * run);
        a0 = fmaf(w, U0[idx], a0);
        a1 = fmaf(w, U1[idx], a1);
    }
    float o0 = CABS * (a0 * r0r + a1 * r1r);
    float o1 = CABS * (a0 * r0g + a1 * r1g);
    float o2 = CABS * (a0 * r0b + a1 * r1b);
    out[0 * SS2 + col] = fminf(fmaxf(o0, 0.0f), 1.0f);
    out[1 * SS2 + col] = fminf(fmaxf(o1, 0.0f), 1.0f);
    out[2 * SS2 + col] = fminf(fmaxf(o2, 0.0f), 1.0f);
}

// ---- fallback path (small workspace): fuse back-rotation into the compositor ----
__global__ __launch_bounds__(64) void k_fused_back(const float* __restrict__ T,
                                                   const float* __restrict__ d,
                                                   float* __restrict__ LA, Mat3 RT,
                                                   float cr, float cg, float cb, int first) {
    int col = blockIdx.x * 64 + threadIdx.x;
    if (col >= SS2) return;
    int y = col / SS, x = col % SS;
    float run = 0.0f, acc = 0.0f;
    for (int z = SS - 1; z >= 0; --z) {
        float qx, qy, qz; qmap(RT, x + PAD, y + PAD, z + PAD, qx, qy, qz);
        float u = tri_T(T, qz, qy, qx);
        float dv = d[z * SS2 + col];
        run += dv;
        acc = fmaf(dv * __expf(-CABS * run), u, acc);
    }
    if (first) {
        LA[0 * SS2 + col] = acc * cr;
        LA[1 * SS2 + col] = acc * cg;
        LA[2 * SS2 + col] = acc * cb;
    } else {
        LA[0 * SS2 + col] += acc * cr;
        LA[1 * SS2 + col] += acc * cg;
        LA[2 * SS2 + col] += acc * cb;
    }
}

__global__ __launch_bounds__(256) void k_clip(const float* __restrict__ LA, float* __restrict__ out) {
    int i = blockIdx.x * 256 + threadIdx.x;
    if (i < 3 * SS2) out[i] = fminf(fmaxf(CABS * LA[i], 0.0f), 1.0f);
}

// host: build R (ypr) and its transpose (== rot_matrix(-y,-p,'rpy')) as in reference
static void light_mats(const double ld_in[3], Mat3& R, Mat3& RT) {
    double n = sqrt(ld_in[0]*ld_in[0] + ld_in[1]*ld_in[1] + ld_in[2]*ld_in[2]);
    double l0 = ld_in[0]/n, l1 = ld_in[1]/n, l2 = ld_in[2]/n;
    double yv = -asin(l0);
    if (l2 < 0) yv = -M_PI - yv;
    double yd = yv * 180.0 / M_PI, pd = asin(l1) * 180.0 / M_PI;
    double yr = yd * M_PI / 180.0, pr = pd * M_PI / 180.0;
    float cy = (float)cos(yr), sy = (float)sin(yr), cp = (float)cos(pr), sp = (float)sin(pr);
    float m[9] = { cy,  sy*sp,  sy*cp,
                   0.f, cp,    -sp,
                  -sy,  cy*sp,  cy*cp };
    for (int i = 0; i < 9; ++i) R.m[i] = m[i];
    RT.m[0] = m[0]; RT.m[1] = m[3]; RT.m[2] = m[6];
    RT.m[3] = m[1]; RT.m[4] = m[4]; RT.m[5] = m[7];
    RT.m[6] = m[2]; RT.m[7] = m[5]; RT.m[8] = m[8];
}

extern "C" void kernel_launch(void* const* d_in, const int* in_sizes, int n_in,
                              void* d_out, int out_size, void* d_ws, size_t ws_size,
                              hipStream_t stream) {
    const float* d = (const float*)d_in[0];
    float* out = (float*)d_out;
    float* T = (float*)d_ws;

    const double dirs[2][3] = { {2.0, 1.0, 1.0}, {-1.0, 0.5, 0.0} };
    const float rgb[2][3] = { {1.0f, 69.0f/255.0f, 25.0f/255.0f},
                              {227.0f/255.0f, 1.0f, 66.0f/255.0f} };

    const size_t need_fast = (size_t)(LL3 + 2 * SS3) * sizeof(float);
    bool fast = ws_size >= need_fast;

    if (fast) {
        float* U0 = T + LL3;
        float* U1 = U0 + SS3;
        for (int l = 0; l < 2; ++l) {
            Mat3 R, RT;
            light_mats(dirs[l], R, RT);
            k_rot_density<<<(LL3 + 255) / 256, 256, 0, stream>>>(d, T, R);
            k_scan_exp  <<<(LL2 + 63) / 64, 64, 0, stream>>>(T, R);
            k_rot_back  <<<(SS3 + 255) / 256, 256, 0, stream>>>(T, l ? U1 : U0, RT);
        }
        k_finalize<<<(SS2 + 63) / 64, 64, 0, stream>>>(d, U0, U1, out,
            rgb[0][0], rgb[0][1], rgb[0][2], rgb[1][0], rgb[1][1], rgb[1][2]);
    } else {
        float* LA = T + LL3;   // 3*SS2 floats
        for (int l = 0; l < 2; ++l) {
            Mat3 R, RT;
            light_mats(dirs[l], R, RT);
            k_rot_density<<<(LL3 + 255) / 256, 256, 0, stream>>>(d, T, R);
            k_scan_exp  <<<(LL2 + 63) / 64, 64, 0, stream>>>(T, R);
            k_fused_back<<<(SS2 + 63) / 64, 64, 0, stream>>>(T, d, LA, RT,
                rgb[l][0], rgb[l][1], rgb[l][2], l == 0);
        }
        k_clip<<<(3 * SS2 + 255) / 256, 256, 0, stream>>>(LA, out);
    }
}

// Round 3
// 351.695 us; speedup vs baseline: 1.3122x; 1.3122x over previous
//
#include <hip/hip_runtime.h>
#include <math.h>

#ifndef M_PI
#define M_PI 3.14159265358979323846
#endif

// Static problem config (mirrors reference)
#define SS   129                 // density cube side
#define LL   224                 // padded/rotation cube side = ceil(129*sqrt(3))
#define LL2  (LL*LL)
#define LL3  (LL*LL*LL)
#define SS2  (SS*SS)
#define SS3  (SS*SS*SS)
#define CABS 0.2f
#define PAD  48                  // LL/2 - SS/2 = 112 - 64

// Slab bounds in forward-rotated grid coords (q-space):
// density-touch region is (47,177); rotate-back taps reach [46.27,177.73]
// (crop cells 48..176 plus ||delta||_2 <= sqrt(3) rotated tap offset).
#define BLO 45.5f
#define BHI 178.5f

// blocks per light
#define BPL1 43904               // LL3/256 exactly
#define BPL2 196                 // LL2/256 exactly
#define BPL3 8387                // ceil(SS3/256)

struct Mat3 { float m[9]; };

// linspace(-1, 1, 224)[i]
__device__ __forceinline__ float nrm(int i) {
    return fmaf((float)i, 2.0f / 223.0f, -1.0f);
}

// forward map p -> q (padded-grid coords of the rotated sample point).
// Single shared expression for K1 and K2 (bitwise consistency of in_slab).
__device__ __forceinline__ void qmap(const Mat3& M, int x, int y, int z,
                                     float& qx, float& qy, float& qz) {
    float bx = nrm(x), by = nrm(y), bz = nrm(z);
    float sx = fmaf(M.m[0], bx, fmaf(M.m[1], by, M.m[2] * bz));
    float sy = fmaf(M.m[3], bx, fmaf(M.m[4], by, M.m[5] * bz));
    float sz = fmaf(M.m[6], bx, fmaf(M.m[7], by, M.m[8] * bz));
    qx = fmaf(sx, 111.5f, 111.5f);   // (s+1)*0.5*(LL-1); note d(q)/dz == M.m[k*3+2] exactly
    qy = fmaf(sy, 111.5f, 111.5f);
    qz = fmaf(sz, 111.5f, 111.5f);
}

__device__ __forceinline__ bool in_slab(float qx, float qy, float qz) {
    return !(qx < BLO || qx > BHI || qy < BLO || qy > BHI || qz < BLO || qz > BHI);
}

// padded-volume fetch: zero outside the centered SS^3 region
__device__ __forceinline__ float fetch_d(const float* __restrict__ d, int z, int y, int x) {
    unsigned zz = (unsigned)(z - PAD), yy = (unsigned)(y - PAD), xx = (unsigned)(x - PAD);
    return (zz < (unsigned)SS && yy < (unsigned)SS && xx < (unsigned)SS)
        ? d[((int)zz * SS + (int)yy) * SS + (int)xx] : 0.0f;
}

// transmittance-volume fetch: zero outside [0,LL)^3
__device__ __forceinline__ float fetch_T(const float* __restrict__ T, int z, int y, int x) {
    unsigned zz = (unsigned)z, yy = (unsigned)y, xx = (unsigned)x;
    return (zz < (unsigned)LL && yy < (unsigned)LL && xx < (unsigned)LL)
        ? T[((int)zz * LL + (int)yy) * LL + (int)xx] : 0.0f;
}

__device__ __forceinline__ float tri_d(const float* __restrict__ d, float qz, float qy, float qx) {
    int x0 = (int)floorf(qx), y0 = (int)floorf(qy), z0 = (int)floorf(qz);
    float wx = qx - (float)x0, wy = qy - (float)y0, wz = qz - (float)z0;
    float c000 = fetch_d(d, z0,     y0,     x0    );
    float c001 = fetch_d(d, z0,     y0,     x0 + 1);
    float c010 = fetch_d(d, z0,     y0 + 1, x0    );
    float c011 = fetch_d(d, z0,     y0 + 1, x0 + 1);
    float c100 = fetch_d(d, z0 + 1, y0,     x0    );
    float c101 = fetch_d(d, z0 + 1, y0,     x0 + 1);
    float c110 = fetch_d(d, z0 + 1, y0 + 1, x0    );
    float c111 = fetch_d(d, z0 + 1, y0 + 1, x0 + 1);
    float a00 = c000 + wx * (c001 - c000);
    float a01 = c010 + wx * (c011 - c010);
    float a10 = c100 + wx * (c101 - c100);
    float a11 = c110 + wx * (c111 - c110);
    float b0  = a00 + wy * (a01 - a00);
    float b1  = a10 + wy * (a11 - a10);
    return b0 + wz * (b1 - b0);
}

__device__ __forceinline__ float tri_T(const float* __restrict__ T, float qz, float qy, float qx) {
    int x0 = (int)floorf(qx), y0 = (int)floorf(qy), z0 = (int)floorf(qz);
    float wx = qx - (float)x0, wy = qy - (float)y0, wz = qz - (float)z0;
    float c000 = fetch_T(T, z0,     y0,     x0    );
    float c001 = fetch_T(T, z0,     y0,     x0 + 1);
    float c010 = fetch_T(T, z0,     y0 + 1, x0    );
    float c011 = fetch_T(T, z0,     y0 + 1, x0 + 1);
    float c100 = fetch_T(T, z0 + 1, y0,     x0    );
    float c101 = fetch_T(T, z0 + 1, y0,     x0 + 1);
    float c110 = fetch_T(T, z0 + 1, y0 + 1, x0    );
    float c111 = fetch_T(T, z0 + 1, y0 + 1, x0 + 1);
    float a00 = c000 + wx * (c001 - c000);
    float a01 = c010 + wx * (c011 - c010);
    float a10 = c100 + wx * (c101 - c100);
    float a11 = c110 + wx * (c111 - c110);
    float b0  = a00 + wy * (a01 - a00);
    float b1  = a10 + wy * (a11 - a10);
    return b0 + wz * (b1 - b0);
}

// K1: rotated density for both lights, slab-restricted
__global__ __launch_bounds__(256) void k_rot_density(const float* __restrict__ d,
                                                     float* __restrict__ T0,
                                                     float* __restrict__ T1,
                                                     Mat3 R0, Mat3 R1, int lbase) {
    int b = blockIdx.x;
    int lofs = b / BPL1;
    int i = (b - lofs * BPL1) * 256 + threadIdx.x;       // < LL3 exactly
    int light = lbase + lofs;
    const Mat3 R = light ? R1 : R0;
    float* __restrict__ T = light ? T1 : T0;
    int x = i % LL; int r = i / LL; int y = r % LL; int z = r / LL;
    float qx, qy, qz; qmap(R, x, y, z, qx, qy, qz);
    if (!in_slab(qx, qy, qz)) return;
    T[i] = tri_d(d, qz, qy, qx);
}

// K2: reverse cumsum + exp over each column's exact in-slab interval, batched loads
__global__ __launch_bounds__(256) void k_scan_exp(float* __restrict__ T0,
                                                  float* __restrict__ T1,
                                                  Mat3 R0, Mat3 R1, int lbase) {
    int b = blockIdx.x;
    int lofs = b / BPL2;
    int col = (b - lofs * BPL2) * 256 + threadIdx.x;     // < LL2 exactly
    int light = lbase + lofs;
    const Mat3 R = light ? R1 : R0;
    float* __restrict__ Tc = (light ? T1 : T0) + col;
    int x = col % LL, y = col / LL;

    // conservative bracket from linear model q_k(z) = q_k(0) + z*R[k][2]
    float q0x, q0y, q0z; qmap(R, x, y, 0, q0x, q0y, q0z);
    float q0[3] = { q0x, q0y, q0z };
    float zlo = 0.0f, zhi = 223.0f;
    #pragma unroll
    for (int k = 0; k < 3; ++k) {
        float m = R.m[k * 3 + 2];
        if (fabsf(m) > 1e-6f) {
            float t0 = (BLO - q0[k]) / m, t1 = (BHI - q0[k]) / m;
            zlo = fmaxf(zlo, fminf(t0, t1));
            zhi = fminf(zhi, fmaxf(t0, t1));
        } else if (q0[k] < BLO || q0[k] > BHI) {
            return;
        }
    }
    int zb1 = min(223, (int)floorf(zhi) + 3);
    int zb0 = max(0,   (int)ceilf(zlo)  - 3);
    if (zb0 > zb1) return;

    // exact endpoints (same fp test as K1 -> read set == write set); slopes >=0.4
    // per z-step make the in-slab set contiguous, so endpoint scans are short.
    int ztop = zb1 + 1;
    while (--ztop >= zb0) {
        float qx, qy, qz; qmap(R, x, y, ztop, qx, qy, qz);
        if (in_slab(qx, qy, qz)) break;
    }
    if (ztop < zb0) return;
    int zbot = zb0 - 1;
    while (++zbot < ztop) {
        float qx, qy, qz; qmap(R, x, y, zbot, qx, qy, qz);
        if (in_slab(qx, qy, qz)) break;
    }

    // batched scan: chunks of 8 independent loads, then exp+stores.
    // Final chunk pads by clamping z to >=0: padded cells are below the slab
    // (never read by K3), padded reads only contaminate `run` after all real cells.
    float run = 0.0f;
    int z = ztop;
    int nchunks = (ztop - zbot + 8) >> 3;
    for (int c = 0; c < nchunks; ++c) {
        float v[8];
        #pragma unroll
        for (int j = 0; j < 8; ++j) {
            int zz = max(z - j, 0);
            v[j] = Tc[zz * LL2];
        }
        #pragma unroll
        for (int j = 0; j < 8; ++j) {
            run += v[j];
            v[j] = __expf(-CABS * run);
        }
        #pragma unroll
        for (int j = 0; j < 8; ++j) {
            int zz = max(z - j, 0);
            Tc[zz * LL2] = v[j];
        }
        z -= 8;
    }
}

// K3: rotate transmittance back (RT = R^T), cropped to the SS^3 center
__global__ __launch_bounds__(256) void k_rot_back(const float* __restrict__ T0,
                                                  const float* __restrict__ T1,
                                                  float* __restrict__ U0,
                                                  float* __restrict__ U1,
                                                  Mat3 RT0, Mat3 RT1, int lbase) {
    int b = blockIdx.x;
    int lofs = b / BPL3;
    int i = (b - lofs * BPL3) * 256 + threadIdx.x;
    if (i >= SS3) return;
    int light = lbase + lofs;
    const Mat3 RT = light ? RT1 : RT0;
    const float* __restrict__ T = light ? T1 : T0;
    float* __restrict__ U = light ? U1 : U0;
    int x = i % SS; int r = i / SS; int y = r % SS; int z = r / SS;
    float qx, qy, qz; qmap(RT, x + PAD, y + PAD, z + PAD, qx, qy, qz);
    U[i] = tri_T(T, qz, qy, qx);
}

// K4: composite along view ray, batched loads (24 in flight per chunk)
__global__ __launch_bounds__(64) void k_finalize(const float* __restrict__ d,
                                                 const float* __restrict__ U0,
                                                 const float* __restrict__ U1,
                                                 float* __restrict__ out,
                                                 float r0r, float r0g, float r0b,
                                                 float r1r, float r1g, float r1b) {
    int col = blockIdx.x * 64 + threadIdx.x;
    if (col >= SS2) return;
    float run = 0.0f, a0 = 0.0f, a1 = 0.0f;
    int z = SS - 1;                    // 128
    {   // head (129 = 1 + 16*8)
        int idx = z * SS2 + col;
        float dv = d[idx];
        run += dv;
        float w = dv * __expf(-CABS * run);
        a0 = fmaf(w, U0[idx], a0);
        a1 = fmaf(w, U1[idx], a1);
        --z;
    }
    for (int c = 0; c < 16; ++c) {
        float dv[8], u0[8], u1[8];
        #pragma unroll
        for (int j = 0; j < 8; ++j) {
            int idx = (z - j) * SS2 + col;
            dv[j] = d[idx]; u0[j] = U0[idx]; u1[j] = U1[idx];
        }
        #pragma unroll
        for (int j = 0; j < 8; ++j) {
            run += dv[j];
            float w = dv[j] * __expf(-CABS * run);
            a0 = fmaf(w, u0[j], a0);
            a1 = fmaf(w, u1[j], a1);
        }
        z -= 8;
    }
    float o0 = CABS * (a0 * r0r + a1 * r1r);
    float o1 = CABS * (a0 * r0g + a1 * r1g);
    float o2 = CABS * (a0 * r0b + a1 * r1b);
    out[0 * SS2 + col] = fminf(fmaxf(o0, 0.0f), 1.0f);
    out[1 * SS2 + col] = fminf(fmaxf(o1, 0.0f), 1.0f);
    out[2 * SS2 + col] = fminf(fmaxf(o2, 0.0f), 1.0f);
}

// ---- smallest-workspace fallback: fuse back-rotation into the compositor ----
__global__ __launch_bounds__(64) void k_fused_back(const float* __restrict__ T,
                                                   const float* __restrict__ d,
                                                   float* __restrict__ LA, Mat3 RT,
                                                   float cr, float cg, float cb, int first) {
    int col = blockIdx.x * 64 + threadIdx.x;
    if (col >= SS2) return;
    int y = col / SS, x = col % SS;
    float run = 0.0f, acc = 0.0f;
    for (int z = SS - 1; z >= 0; --z) {
        float qx, qy, qz; qmap(RT, x + PAD, y + PAD, z + PAD, qx, qy, qz);
        float u = tri_T(T, qz, qy, qx);
        float dv = d[z * SS2 + col];
        run += dv;
        acc = fmaf(dv * __expf(-CABS * run), u, acc);
    }
    if (first) {
        LA[0 * SS2 + col] = acc * cr;
        LA[1 * SS2 + col] = acc * cg;
        LA[2 * SS2 + col] = acc * cb;
    } else {
        LA[0 * SS2 + col] += acc * cr;
        LA[1 * SS2 + col] += acc * cg;
        LA[2 * SS2 + col] += acc * cb;
    }
}

__global__ __launch_bounds__(256) void k_clip(const float* __restrict__ LA, float* __restrict__ out) {
    int i = blockIdx.x * 256 + threadIdx.x;
    if (i < 3 * SS2) out[i] = fminf(fmaxf(CABS * LA[i], 0.0f), 1.0f);
}

// host: build R (ypr) and its transpose (== rot_matrix(-y,-p,'rpy')) as in reference
static void light_mats(const double ld_in[3], Mat3& R, Mat3& RT) {
    double n = sqrt(ld_in[0]*ld_in[0] + ld_in[1]*ld_in[1] + ld_in[2]*ld_in[2]);
    double l0 = ld_in[0]/n, l1 = ld_in[1]/n, l2 = ld_in[2]/n;
    double yv = -asin(l0);
    if (l2 < 0) yv = -M_PI - yv;
    double yd = yv * 180.0 / M_PI, pd = asin(l1) * 180.0 / M_PI;
    double yr = yd * M_PI / 180.0, pr = pd * M_PI / 180.0;
    float cy = (float)cos(yr), sy = (float)sin(yr), cp = (float)cos(pr), sp = (float)sin(pr);
    float m[9] = { cy,  sy*sp,  sy*cp,
                   0.f, cp,    -sp,
                  -sy,  cy*sp,  cy*cp };
    for (int i = 0; i < 9; ++i) R.m[i] = m[i];
    RT.m[0] = m[0]; RT.m[1] = m[3]; RT.m[2] = m[6];
    RT.m[3] = m[1]; RT.m[4] = m[4]; RT.m[5] = m[7];
    RT.m[6] = m[2]; RT.m[7] = m[5]; RT.m[8] = m[8];
}

extern "C" void kernel_launch(void* const* d_in, const int* in_sizes, int n_in,
                              void* d_out, int out_size, void* d_ws, size_t ws_size,
                              hipStream_t stream) {
    const float* d = (const float*)d_in[0];
    float* out = (float*)d_out;

    const double dirs[2][3] = { {2.0, 1.0, 1.0}, {-1.0, 0.5, 0.0} };
    const float rgb[2][3] = { {1.0f, 69.0f/255.0f, 25.0f/255.0f},
                              {227.0f/255.0f, 1.0f, 66.0f/255.0f} };
    Mat3 R[2], RT[2];
    light_mats(dirs[0], R[0], RT[0]);
    light_mats(dirs[1], R[1], RT[1]);

    const size_t need_A = (size_t)(2 * LL3 + 2 * SS3) * sizeof(float);   // ~107 MB
    const size_t need_B = (size_t)(LL3 + 2 * SS3) * sizeof(float);       // ~62 MB

    if (ws_size >= need_A) {
        float* T0 = (float*)d_ws;
        float* T1 = T0 + LL3;
        float* U0 = T1 + LL3;
        float* U1 = U0 + SS3;
        k_rot_density<<<2 * BPL1, 256, 0, stream>>>(d, T0, T1, R[0], R[1], 0);
        k_scan_exp   <<<2 * BPL2, 256, 0, stream>>>(T0, T1, R[0], R[1], 0);
        k_rot_back   <<<2 * BPL3, 256, 0, stream>>>(T0, T1, U0, U1, RT[0], RT[1], 0);
        k_finalize   <<<(SS2 + 63) / 64, 64, 0, stream>>>(d, U0, U1, out,
            rgb[0][0], rgb[0][1], rgb[0][2], rgb[1][0], rgb[1][1], rgb[1][2]);
    } else if (ws_size >= need_B) {
        float* T  = (float*)d_ws;
        float* U0 = T + LL3;
        float* U1 = U0 + SS3;
        for (int l = 0; l < 2; ++l) {
            k_rot_density<<<BPL1, 256, 0, stream>>>(d, T, T, R[0], R[1], l);
            k_scan_exp   <<<BPL2, 256, 0, stream>>>(T, T, R[0], R[1], l);
            k_rot_back   <<<BPL3, 256, 0, stream>>>(T, T, U0, U1, RT[0], RT[1], l);
        }
        k_finalize<<<(SS2 + 63) / 64, 64, 0, stream>>>(d, U0, U1, out,
            rgb[0][0], rgb[0][1], rgb[0][2], rgb[1][0], rgb[1][1], rgb[1][2]);
    } else {
        float* T  = (float*)d_ws;
        float* LA = T + LL3;
        for (int l = 0; l < 2; ++l) {
            k_rot_density<<<BPL1, 256, 0, stream>>>(d, T, T, R[0], R[1], l);
            k_scan_exp   <<<BPL2, 256, 0, stream>>>(T, T, R[0], R[1], l);
            k_fused_back <<<(SS2 + 63) / 64, 64, 0, stream>>>(T, d, LA, RT[l],
                rgb[l][0], rgb[l][1], rgb[l][2], l == 0);
        }
        k_clip<<<(3 * SS2 + 255) / 256, 256, 0, stream>>>(LA, out);
    }
}

// Round 4
// 225.739 us; speedup vs baseline: 2.0444x; 1.5580x over previous
//
#include <hip/hip_runtime.h>
#include <math.h>

#ifndef M_PI
#define M_PI 3.14159265358979323846
#endif

// Static problem config (mirrors reference)
#define SS   129                 // density cube side
#define LL   224                 // padded/rotation cube side = ceil(129*sqrt(3))
#define LL2  (LL*LL)
#define LL3  (LL*LL*LL)
#define SS2  (SS*SS)
#define SS3  (SS*SS*SS)
#define CABS 0.2f
#define PAD  48                  // LL/2 - SS/2 = 112 - 64

// Slab bounds in forward-rotated grid coords (q-space)
#define BLO 45.5f
#define BHI 178.5f

#define BPL2 196                 // LL2/256 exactly (scan blocks per light)

// gather tiling: 8x8x8 output tile per 512-thread block, fixed LDS source box
#define GLX 16
#define GLY 13
#define GLZ 15
#define GLN (GLX*GLY*GLZ)        // 3120 floats = 12.5 KB

struct Mat3 { float m[9]; };
struct F3   { float x, y, z; };

// linspace(-1, 1, 224)[i]
__device__ __forceinline__ float nrm(int i) {
    return fmaf((float)i, 2.0f / 223.0f, -1.0f);
}

// forward map p -> q. Single shared expression for K1 write-predicate and K2
// read-predicate (bitwise consistency).
__device__ __forceinline__ void qmap(const Mat3& M, int x, int y, int z,
                                     float& qx, float& qy, float& qz) {
    float bx = nrm(x), by = nrm(y), bz = nrm(z);
    float sx = fmaf(M.m[0], bx, fmaf(M.m[1], by, M.m[2] * bz));
    float sy = fmaf(M.m[3], bx, fmaf(M.m[4], by, M.m[5] * bz));
    float sz = fmaf(M.m[6], bx, fmaf(M.m[7], by, M.m[8] * bz));
    qx = fmaf(sx, 111.5f, 111.5f);   // grid step maps to exactly 1 voxel
    qy = fmaf(sy, 111.5f, 111.5f);
    qz = fmaf(sz, 111.5f, 111.5f);
}

__device__ __forceinline__ bool in_slab(float qx, float qy, float qz) {
    return !(qx < BLO || qx > BHI || qy < BLO || qy > BHI || qz < BLO || qz > BHI);
}

// padded-volume fetch: zero outside the centered SS^3 region
__device__ __forceinline__ float fetch_d(const float* __restrict__ d, int z, int y, int x) {
    unsigned zz = (unsigned)(z - PAD), yy = (unsigned)(y - PAD), xx = (unsigned)(x - PAD);
    return (zz < (unsigned)SS && yy < (unsigned)SS && xx < (unsigned)SS)
        ? d[((int)zz * SS + (int)yy) * SS + (int)xx] : 0.0f;
}

// transmittance-volume fetch: zero outside [0,LL)^3
__device__ __forceinline__ float fetch_T(const float* __restrict__ T, int z, int y, int x) {
    unsigned zz = (unsigned)z, yy = (unsigned)y, xx = (unsigned)x;
    return (zz < (unsigned)LL && yy < (unsigned)LL && xx < (unsigned)LL)
        ? T[((int)zz * LL + (int)yy) * LL + (int)xx] : 0.0f;
}

__device__ __forceinline__ float tri_T(const float* __restrict__ T, float qz, float qy, float qx) {
    int x0 = (int)floorf(qx), y0 = (int)floorf(qy), z0 = (int)floorf(qz);
    float wx = qx - (float)x0, wy = qy - (float)y0, wz = qz - (float)z0;
    float c000 = fetch_T(T, z0,     y0,     x0    );
    float c001 = fetch_T(T, z0,     y0,     x0 + 1);
    float c010 = fetch_T(T, z0,     y0 + 1, x0    );
    float c011 = fetch_T(T, z0,     y0 + 1, x0 + 1);
    float c100 = fetch_T(T, z0 + 1, y0,     x0    );
    float c101 = fetch_T(T, z0 + 1, y0,     x0 + 1);
    float c110 = fetch_T(T, z0 + 1, y0 + 1, x0    );
    float c111 = fetch_T(T, z0 + 1, y0 + 1, x0 + 1);
    float a00 = c000 + wx * (c001 - c000);
    float a01 = c010 + wx * (c011 - c010);
    float a10 = c100 + wx * (c101 - c100);
    float a11 = c110 + wx * (c111 - c110);
    float b0  = a00 + wy * (a01 - a00);
    float b1  = a10 + wy * (a11 - a10);
    return b0 + wz * (b1 - b0);
}

// Tiled LDS-staged rotation-resample.
// IS_K1: src=d (PAD-offset, zero-pad), dst=T over 224^3, write iff in_slab.
// !IS_K1: src=T (zero outside), dst=U over 129^3 crop, coords +PAD.
// NT = tiles per axis, OE = output extent.
template<bool IS_K1, int OE, int NT>
__global__ __launch_bounds__(512) void k_gather(const float* __restrict__ src,
                                                float* __restrict__ dst0,
                                                float* __restrict__ dst1,
                                                Mat3 M0, Mat3 M1, F3 H0, F3 H1,
                                                int lbase) {
    const int TPL = NT * NT * NT;
    int b = blockIdx.x;
    int lofs = b / TPL; b -= lofs * TPL;
    int light = lbase + lofs;
    const Mat3 M = light ? M1 : M0;
    const F3  H  = light ? H1 : H0;
    float* __restrict__ dst = light ? dst1 : dst0;

    int ttx = b % NT; int rr = b / NT; int tty = rr % NT; int ttz = rr / NT;
    int ox = ttx * 8, oy = tty * 8, oz = ttz * 8;
    const int OFS = IS_K1 ? 0 : PAD;

    // tile-center q (float version of qmap; only used for AABB, margin in H)
    float cbx = fmaf((float)(ox + OFS) + 3.5f, 2.0f / 223.0f, -1.0f);
    float cby = fmaf((float)(oy + OFS) + 3.5f, 2.0f / 223.0f, -1.0f);
    float cbz = fmaf((float)(oz + OFS) + 3.5f, 2.0f / 223.0f, -1.0f);
    float qcx = fmaf(fmaf(M.m[0], cbx, fmaf(M.m[1], cby, M.m[2] * cbz)), 111.5f, 111.5f);
    float qcy = fmaf(fmaf(M.m[3], cbx, fmaf(M.m[4], cby, M.m[5] * cbz)), 111.5f, 111.5f);
    float qcz = fmaf(fmaf(M.m[6], cbx, fmaf(M.m[7], cby, M.m[8] * cbz)), 111.5f, 111.5f);

    if (IS_K1) {
        // whole-tile slab rejection (uniform branch, before staging)
        if (qcx + H.x < BLO || qcx - H.x > BHI ||
            qcy + H.y < BLO || qcy - H.y > BHI ||
            qcz + H.z < BLO || qcz - H.z > BHI) return;
    }

    int lox = (int)floorf(qcx - H.x);
    int loy = (int)floorf(qcy - H.y);
    int loz = (int)floorf(qcz - H.z);

    __shared__ float S[GLZ][GLY][GLX];
    for (int idx = threadIdx.x; idx < GLN; idx += 512) {
        int ix = idx % GLX; int t2 = idx / GLX; int iy = t2 % GLY; int iz = t2 / GLY;
        int gx = lox + ix, gy = loy + iy, gz = loz + iz;
        S[iz][iy][ix] = IS_K1 ? fetch_d(src, gz, gy, gx) : fetch_T(src, gz, gy, gx);
    }
    __syncthreads();

    int lx = threadIdx.x & 7, ly = (threadIdx.x >> 3) & 7, lz = threadIdx.x >> 6;
    int x = ox + lx, y = oy + ly, z = oz + lz;
    if (!IS_K1 && (x >= OE || y >= OE || z >= OE)) return;

    float qx, qy, qz; qmap(M, x + OFS, y + OFS, z + OFS, qx, qy, qz);
    if (IS_K1 && !in_slab(qx, qy, qz)) return;

    int gx0 = (int)floorf(qx), gy0 = (int)floorf(qy), gz0 = (int)floorf(qz);
    float wx = qx - (float)gx0, wy = qy - (float)gy0, wz = qz - (float)gz0;
    int x0 = gx0 - lox, y0 = gy0 - loy, z0 = gz0 - loz;

    float c000 = S[z0    ][y0    ][x0    ];
    float c001 = S[z0    ][y0    ][x0 + 1];
    float c010 = S[z0    ][y0 + 1][x0    ];
    float c011 = S[z0    ][y0 + 1][x0 + 1];
    float c100 = S[z0 + 1][y0    ][x0    ];
    float c101 = S[z0 + 1][y0    ][x0 + 1];
    float c110 = S[z0 + 1][y0 + 1][x0    ];
    float c111 = S[z0 + 1][y0 + 1][x0 + 1];
    float a00 = c000 + wx * (c001 - c000);
    float a01 = c010 + wx * (c011 - c010);
    float a10 = c100 + wx * (c101 - c100);
    float a11 = c110 + wx * (c111 - c110);
    float b0  = a00 + wy * (a01 - a00);
    float b1  = a10 + wy * (a11 - a10);
    float v   = b0 + wz * (b1 - b0);

    if (IS_K1) dst[(z * LL + y) * LL + x] = v;
    else       dst[(z * SS + y) * SS + x] = v;
}

// K2: reverse cumsum + exp over each column's exact in-slab interval, batched loads
__global__ __launch_bounds__(256) void k_scan_exp(float* __restrict__ T0,
                                                  float* __restrict__ T1,
                                                  Mat3 R0, Mat3 R1, int lbase) {
    int b = blockIdx.x;
    int lofs = b / BPL2;
    int col = (b - lofs * BPL2) * 256 + threadIdx.x;     // < LL2 exactly
    int light = lbase + lofs;
    const Mat3 R = light ? R1 : R0;
    float* __restrict__ Tc = (light ? T1 : T0) + col;
    int x = col % LL, y = col / LL;

    // conservative bracket from linear model q_k(z) = q_k(0) + z*R[k][2]
    float q0x, q0y, q0z; qmap(R, x, y, 0, q0x, q0y, q0z);
    float q0[3] = { q0x, q0y, q0z };
    float zlo = 0.0f, zhi = 223.0f;
    #pragma unroll
    for (int k = 0; k < 3; ++k) {
        float m = R.m[k * 3 + 2];
        if (fabsf(m) > 1e-6f) {
            float t0 = (BLO - q0[k]) / m, t1 = (BHI - q0[k]) / m;
            zlo = fmaxf(zlo, fminf(t0, t1));
            zhi = fminf(zhi, fmaxf(t0, t1));
        } else if (q0[k] < BLO || q0[k] > BHI) {
            return;
        }
    }
    int zb1 = min(223, (int)floorf(zhi) + 3);
    int zb0 = max(0,   (int)ceilf(zlo)  - 3);
    if (zb0 > zb1) return;

    // exact endpoints (same fp test as K1's write predicate)
    int ztop = zb1 + 1;
    while (--ztop >= zb0) {
        float qx, qy, qz; qmap(R, x, y, ztop, qx, qy, qz);
        if (in_slab(qx, qy, qz)) break;
    }
    if (ztop < zb0) return;
    int zbot = zb0 - 1;
    while (++zbot < ztop) {
        float qx, qy, qz; qmap(R, x, y, zbot, qx, qy, qz);
        if (in_slab(qx, qy, qz)) break;
    }

    // batched scan: chunks of 8 independent loads, then exp+stores.
    float run = 0.0f;
    int z = ztop;
    int nchunks = (ztop - zbot + 8) >> 3;
    for (int c = 0; c < nchunks; ++c) {
        float v[8];
        #pragma unroll
        for (int j = 0; j < 8; ++j) {
            int zz = max(z - j, 0);
            v[j] = Tc[zz * LL2];
        }
        #pragma unroll
        for (int j = 0; j < 8; ++j) {
            run += v[j];
            v[j] = __expf(-CABS * run);
        }
        #pragma unroll
        for (int j = 0; j < 8; ++j) {
            int zz = max(z - j, 0);
            Tc[zz * LL2] = v[j];
        }
        z -= 8;
    }
}

// K4: composite along view ray, batched loads
__global__ __launch_bounds__(64) void k_finalize(const float* __restrict__ d,
                                                 const float* __restrict__ U0,
                                                 const float* __restrict__ U1,
                                                 float* __restrict__ out,
                                                 float r0r, float r0g, float r0b,
                                                 float r1r, float r1g, float r1b) {
    int col = blockIdx.x * 64 + threadIdx.x;
    if (col >= SS2) return;
    float run = 0.0f, a0 = 0.0f, a1 = 0.0f;
    int z = SS - 1;                    // 128
    {
        int idx = z * SS2 + col;
        float dv = d[idx];
        run += dv;
        float w = dv * __expf(-CABS * run);
        a0 = fmaf(w, U0[idx], a0);
        a1 = fmaf(w, U1[idx], a1);
        --z;
    }
    for (int c = 0; c < 16; ++c) {
        float dv[8], u0[8], u1[8];
        #pragma unroll
        for (int j = 0; j < 8; ++j) {
            int idx = (z - j) * SS2 + col;
            dv[j] = d[idx]; u0[j] = U0[idx]; u1[j] = U1[idx];
        }
        #pragma unroll
        for (int j = 0; j < 8; ++j) {
            run += dv[j];
            float w = dv[j] * __expf(-CABS * run);
            a0 = fmaf(w, u0[j], a0);
            a1 = fmaf(w, u1[j], a1);
        }
        z -= 8;
    }
    float o0 = CABS * (a0 * r0r + a1 * r1r);
    float o1 = CABS * (a0 * r0g + a1 * r1g);
    float o2 = CABS * (a0 * r0b + a1 * r1b);
    out[0 * SS2 + col] = fminf(fmaxf(o0, 0.0f), 1.0f);
    out[1 * SS2 + col] = fminf(fmaxf(o1, 0.0f), 1.0f);
    out[2 * SS2 + col] = fminf(fmaxf(o2, 0.0f), 1.0f);
}

// ---- smallest-workspace fallback: fuse back-rotation into the compositor ----
__global__ __launch_bounds__(64) void k_fused_back(const float* __restrict__ T,
                                                   const float* __restrict__ d,
                                                   float* __restrict__ LA, Mat3 RT,
                                                   float cr, float cg, float cb, int first) {
    int col = blockIdx.x * 64 + threadIdx.x;
    if (col >= SS2) return;
    int y = col / SS, x = col % SS;
    float run = 0.0f, acc = 0.0f;
    for (int z = SS - 1; z >= 0; --z) {
        float qx, qy, qz; qmap(RT, x + PAD, y + PAD, z + PAD, qx, qy, qz);
        float u = tri_T(T, qz, qy, qx);
        float dv = d[z * SS2 + col];
        run += dv;
        acc = fmaf(dv * __expf(-CABS * run), u, acc);
    }
    if (first) {
        LA[0 * SS2 + col] = acc * cr;
        LA[1 * SS2 + col] = acc * cg;
        LA[2 * SS2 + col] = acc * cb;
    } else {
        LA[0 * SS2 + col] += acc * cr;
        LA[1 * SS2 + col] += acc * cg;
        LA[2 * SS2 + col] += acc * cb;
    }
}

__global__ __launch_bounds__(256) void k_clip(const float* __restrict__ LA, float* __restrict__ out) {
    int i = blockIdx.x * 256 + threadIdx.x;
    if (i < 3 * SS2) out[i] = fminf(fmaxf(CABS * LA[i], 0.0f), 1.0f);
}

// host: build R (ypr) and its transpose (== rot_matrix(-y,-p,'rpy')) as in reference
static void light_mats(const double ld_in[3], Mat3& R, Mat3& RT) {
    double n = sqrt(ld_in[0]*ld_in[0] + ld_in[1]*ld_in[1] + ld_in[2]*ld_in[2]);
    double l0 = ld_in[0]/n, l1 = ld_in[1]/n, l2 = ld_in[2]/n;
    double yv = -asin(l0);
    if (l2 < 0) yv = -M_PI - yv;
    double yd = yv * 180.0 / M_PI, pd = asin(l1) * 180.0 / M_PI;
    double yr = yd * M_PI / 180.0, pr = pd * M_PI / 180.0;
    float cy = (float)cos(yr), sy = (float)sin(yr), cp = (float)cos(pr), sp = (float)sin(pr);
    float m[9] = { cy,  sy*sp,  sy*cp,
                   0.f, cp,    -sp,
                  -sy,  cy*sp,  cy*cp };
    for (int i = 0; i < 9; ++i) R.m[i] = m[i];
    RT.m[0] = m[0]; RT.m[1] = m[3]; RT.m[2] = m[6];
    RT.m[3] = m[1]; RT.m[4] = m[4]; RT.m[5] = m[7];
    RT.m[6] = m[2]; RT.m[7] = m[5]; RT.m[8] = m[8];
}

// half-span of an 8^3 tile's source AABB (per output axis k: 3.5 * |row_k|_1)
static F3 half_span(const Mat3& M) {
    F3 h;
    h.x = 3.5f * (fabsf(M.m[0]) + fabsf(M.m[1]) + fabsf(M.m[2])) + 0.05f;
    h.y = 3.5f * (fabsf(M.m[3]) + fabsf(M.m[4]) + fabsf(M.m[5])) + 0.05f;
    h.z = 3.5f * (fabsf(M.m[6]) + fabsf(M.m[7]) + fabsf(M.m[8])) + 0.05f;
    return h;
}

extern "C" void kernel_launch(void* const* d_in, const int* in_sizes, int n_in,
                              void* d_out, int out_size, void* d_ws, size_t ws_size,
                              hipStream_t stream) {
    const float* d = (const float*)d_in[0];
    float* out = (float*)d_out;

    const double dirs[2][3] = { {2.0, 1.0, 1.0}, {-1.0, 0.5, 0.0} };
    const float rgb[2][3] = { {1.0f, 69.0f/255.0f, 25.0f/255.0f},
                              {227.0f/255.0f, 1.0f, 66.0f/255.0f} };
    Mat3 R[2], RT[2];
    light_mats(dirs[0], R[0], RT[0]);
    light_mats(dirs[1], R[1], RT[1]);
    F3 HF[2] = { half_span(R[0]),  half_span(R[1])  };   // forward rotate
    F3 HB[2] = { half_span(RT[0]), half_span(RT[1]) };   // back rotate

    const int NT1 = LL / 8;            // 28
    const int TPL1 = NT1 * NT1 * NT1;  // 21952
    const int NT3 = (SS + 7) / 8;      // 17
    const int TPL3 = NT3 * NT3 * NT3;  // 4913

    const size_t need_A = (size_t)(2 * LL3 + 2 * SS3) * sizeof(float);   // ~107 MB
    const size_t need_B = (size_t)(LL3 + 2 * SS3) * sizeof(float);       // ~62 MB

    if (ws_size >= need_A) {
        float* T0 = (float*)d_ws;
        float* T1 = T0 + LL3;
        float* U0 = T1 + LL3;
        float* U1 = U0 + SS3;
        k_gather<true,  LL, 28><<<2 * TPL1, 512, 0, stream>>>(d,  T0, T1, R[0],  R[1],  HF[0], HF[1], 0);
        k_scan_exp<<<2 * BPL2, 256, 0, stream>>>(T0, T1, R[0], R[1], 0);
        // back-rotation: each light reads its own T; launch per light on same kernel
        k_gather<false, SS, 17><<<TPL3, 512, 0, stream>>>(T0, U0, U0, RT[0], RT[0], HB[0], HB[0], 0);
        k_gather<false, SS, 17><<<TPL3, 512, 0, stream>>>(T1, U1, U1, RT[1], RT[1], HB[1], HB[1], 0);
        k_finalize<<<(SS2 + 63) / 64, 64, 0, stream>>>(d, U0, U1, out,
            rgb[0][0], rgb[0][1], rgb[0][2], rgb[1][0], rgb[1][1], rgb[1][2]);
    } else if (ws_size >= need_B) {
        float* T  = (float*)d_ws;
        float* U0 = T + LL3;
        float* U1 = U0 + SS3;
        for (int l = 0; l < 2; ++l) {
            k_gather<true,  LL, 28><<<TPL1, 512, 0, stream>>>(d, T, T, R[0], R[1], HF[l], HF[l], l);
            k_scan_exp<<<BPL2, 256, 0, stream>>>(T, T, R[0], R[1], l);
            k_gather<false, SS, 17><<<TPL3, 512, 0, stream>>>(T, l ? U1 : U0, l ? U1 : U0,
                                                              RT[l], RT[l], HB[l], HB[l], 0);
        }
        k_finalize<<<(SS2 + 63) / 64, 64, 0, stream>>>(d, U0, U1, out,
            rgb[0][0], rgb[0][1], rgb[0][2], rgb[1][0], rgb[1][1], rgb[1][2]);
    } else {
        float* T  = (float*)d_ws;
        float* LA = T + LL3;
        for (int l = 0; l < 2; ++l) {
            k_gather<true,  LL, 28><<<TPL1, 512, 0, stream>>>(d, T, T, R[0], R[1], HF[l], HF[l], l);
            k_scan_exp<<<BPL2, 256, 0, stream>>>(T, T, R[0], R[1], l);
            k_fused_back <<<(SS2 + 63) / 64, 64, 0, stream>>>(T, d, LA, RT[l],
                rgb[l][0], rgb[l][1], rgb[l][2], l == 0);
        }
        k_clip<<<(3 * SS2 + 255) / 256, 256, 0, stream>>>(LA, out);
    }
}